// Round 15
// baseline (280.221 us; speedup 1.0000x reference)
//
#include <hip/hip_runtime.h>
#include <math.h>

#define N_NODES 50000
#define N_EDGES 800000
#define DIN 128
#define DHID 128   /* H*HID */
#define NH 4
#define HID 32
#define DOUT 40

#define PB 128      /* dst buckets */
#define NPB 391     /* nodes per bucket: 391*128 = 50048 >= 50000 */

typedef __fp16 fp16x2 __attribute__((ext_vector_type(2)));

static __device__ __forceinline__ float lrelu(float x) { return x > 0.f ? x : 0.2f * x; }

static __device__ __forceinline__ unsigned int pkh(float a, float b) {
    union { fp16x2 h2; unsigned int u; } cv;
    cv.h2 = __builtin_amdgcn_cvt_pkrtz(a, b);
    return cv.u;
}
static __device__ __forceinline__ unsigned short f2h(float a) {
    union { _Float16 h; unsigned short s; } cv;
    cv.h = (_Float16)a;
    return cv.s;
}

// acc[0..7] += p * f16x8(w)  — unpack via f16->f32 (fuses to v_fma_mix)
static __device__ __forceinline__ void fma8(float* acc, uint4 w, float p) {
    union { unsigned int u; _Float16 h[2]; } c0, c1, c2, c3;
    c0.u = w.x; c1.u = w.y; c2.u = w.z; c3.u = w.w;
    acc[0] = fmaf((float)c0.h[0], p, acc[0]);
    acc[1] = fmaf((float)c0.h[1], p, acc[1]);
    acc[2] = fmaf((float)c1.h[0], p, acc[2]);
    acc[3] = fmaf((float)c1.h[1], p, acc[3]);
    acc[4] = fmaf((float)c2.h[0], p, acc[4]);
    acc[5] = fmaf((float)c2.h[1], p, acc[5]);
    acc[6] = fmaf((float)c3.h[0], p, acc[6]);
    acc[7] = fmaf((float)c3.h[1], p, acc[7]);
}

static __device__ __forceinline__ float4 bnelu4(float4 x, float4 sc, float4 sh, float bs) {
    float y0 = fmaf(x.x, sc.x, sh.x);
    float y1 = fmaf(x.y, sc.y, sh.y);
    float y2 = fmaf(x.z, sc.z, sh.z);
    float y3 = fmaf(x.w, sc.w, sh.w);
    y0 = (y0 > 0.f ? y0 : __expf(y0) - 1.f) * bs;
    y1 = (y1 > 0.f ? y1 : __expf(y1) - 1.f) * bs;
    y2 = (y2 > 0.f ? y2 : __expf(y2) - 1.f) * bs;
    y3 = (y3 > 0.f ? y3 : __expf(y3) - 1.f) * bs;
    return {y0, y1, y2, y3};
}

// ================= bucketed CSR build (XCD-local writes) =================
__global__ __launch_bounds__(256) void bucket_hist_kernel(const int* __restrict__ dstv, int* __restrict__ bhist) {
    __shared__ int h[PB];
    if (threadIdx.x < PB) h[threadIdx.x] = 0;
    __syncthreads();
    for (int i = blockIdx.x * blockDim.x + threadIdx.x; i < N_EDGES; i += gridDim.x * blockDim.x)
        atomicAdd(&h[(unsigned)dstv[i] / NPB], 1);
    __syncthreads();
    if (threadIdx.x < PB) atomicAdd(&bhist[threadIdx.x], h[threadIdx.x]);
}

__global__ __launch_bounds__(128) void bucket_scan_kernel(const int* __restrict__ bhist,
                                                          int* __restrict__ bucket_base, int* __restrict__ cursor) {
    __shared__ int sA[PB], sB[PB];
    int t = threadIdx.x;
    sA[t] = bhist[t];
    __syncthreads();
    int* s = sA; int* d2 = sB;
    for (int off = 1; off < PB; off <<= 1) {
        d2[t] = s[t] + (t >= off ? s[t - off] : 0);
        __syncthreads();
        int* tmp = s; s = d2; d2 = tmp;
    }
    int excl = s[t] - bhist[t];
    bucket_base[t] = excl;
    cursor[t] = excl;
    if (t == PB - 1) bucket_base[PB] = s[t];
}

// records packed as (src<<16)|dst — both < 65536
__global__ __launch_bounds__(256) void partition_kernel(const int* __restrict__ srcv, const int* __restrict__ dstv,
                                                        int* __restrict__ cursor, unsigned* __restrict__ part) {
    __shared__ unsigned rec[2048];
    __shared__ int cnt[PB], lofs[PB], gbase[PB];
    __shared__ int sA[PB], sB[PB];
    __shared__ int tot_s;
    const int t = threadIdx.x;
    const int base0 = blockIdx.x * 4096;
    for (int round = 0; round < 2; ++round) {
        int rbase = base0 + round * 2048;
        if (t < PB) cnt[t] = 0;
        __syncthreads();
        int myb[8]; int myr[8]; unsigned myrec[8];
#pragma unroll
        for (int i = 0; i < 8; ++i) {
            int e = rbase + i * 256 + t;
            bool valid = e < N_EDGES;
            int sv = valid ? srcv[e] : 0;
            int dv = valid ? dstv[e] : 0;
            myrec[i] = ((unsigned)sv << 16) | (unsigned)dv;
            int b = (unsigned)dv / NPB;
            myb[i] = valid ? b : -1;
            myr[i] = valid ? atomicAdd(&cnt[b], 1) : 0;
        }
        __syncthreads();
        if (t < PB) sA[t] = cnt[t];
        __syncthreads();
        int* s = sA; int* d2 = sB;
        for (int off = 1; off < PB; off <<= 1) {
            if (t < PB) d2[t] = s[t] + (t >= off ? s[t - off] : 0);
            __syncthreads();
            int* tmp = s; s = d2; d2 = tmp;
        }
        if (t < PB) {
            int c = cnt[t];
            lofs[t] = s[t] - c;
            gbase[t] = c > 0 ? atomicAdd(&cursor[t], c) : 0;
            if (t == PB - 1) tot_s = s[t];
        }
        __syncthreads();
#pragma unroll
        for (int i = 0; i < 8; ++i)
            if (myb[i] >= 0) rec[lofs[myb[i]] + myr[i]] = myrec[i];
        __syncthreads();
        int tot = tot_s;
#pragma unroll
        for (int i = 0; i < 8; ++i) {
            int lp = i * 256 + t;
            if (lp < tot) {
                unsigned r = rec[lp];
                int b = (r & 0xFFFFu) / NPB;
                part[gbase[b] + (lp - lofs[b])] = r;
            }
        }
        __syncthreads();
    }
}

__global__ __launch_bounds__(256) void bucket_csr_kernel(const unsigned* __restrict__ part, const int* __restrict__ bucket_base,
                                                         int* __restrict__ row_ptr, int* __restrict__ csr_src) {
    __shared__ int hist[512], sA[512], sB[512], cur[NPB];
    const int b = blockIdx.x, t = threadIdx.x;
    const int base = bucket_base[b];
    const int n = bucket_base[b + 1] - base;
    hist[t] = 0; hist[t + 256] = 0;
    __syncthreads();
    for (int i = t; i < n; i += 256)
        atomicAdd(&hist[(part[base + i] & 0xFFFFu) - b * NPB], 1);
    __syncthreads();
    sA[t] = hist[t]; sA[t + 256] = hist[t + 256];
    __syncthreads();
    int* s = sA; int* d2 = sB;
    for (int off = 1; off < 512; off <<= 1) {
        d2[t] = s[t] + (t >= off ? s[t - off] : 0);
        int u = t + 256;
        d2[u] = s[u] + (u >= off ? s[u - off] : 0);
        __syncthreads();
        int* tmp = s; s = d2; d2 = tmp;
    }
    for (int j = t; j < NPB; j += 256) {
        int node = b * NPB + j;
        int excl = s[j] - hist[j];
        if (node < N_NODES) row_ptr[node] = base + excl;
        cur[j] = excl;
    }
    if (b == PB - 1 && t == 0) row_ptr[N_NODES] = N_EDGES;
    __syncthreads();
    for (int i = t; i < n; i += 256) {
        unsigned r = part[base + i];
        int loc = (int)(r & 0xFFFFu) - b * NPB;
        int p = atomicAdd(&cur[loc], 1);
        csr_src[base + p] = (int)(r >> 16);
    }
}

// ---------------- gemm128: 64x128 tile per block (+ fused BN-finalize/ELU) + als/ald epilogue ----------------
// 256 thr, 4x8 micro-tile: rows 4ty.., cols {4tx.., 64+4tx..}
__global__ __launch_bounds__(256) void gemm128_kernel(
    const float* __restrict__ X, const float* __restrict__ W,
    const float* __restrict__ a_src, const float* __restrict__ a_dst,
    const float* __restrict__ sums, const float* __restrict__ sqs,
    const float* __restrict__ gamma, const float* __restrict__ beta, float bscale, int apply_bn,
    unsigned int* __restrict__ Hout, float* __restrict__ als, float* __restrict__ ald) {
    __shared__ float Xs[32][68];
    __shared__ float Ws[32][128];
    __shared__ float scale_s[DHID], shift_s[DHID];
    const int t = threadIdx.x;
    const int tx = t & 15, ty = t >> 4;
    const int r0 = blockIdx.x * 64;
    const int sr = t >> 2, sa = t & 3;       // X staging
    const int wk = t >> 5, wc = (t & 31) * 4; // W staging: 8 k-rows x 128 cols per pass, 4 passes

    if (apply_bn && t < DHID) {
        float mu = sums[t] * (1.f / N_NODES);
        float var = sqs[t] * (1.f / N_NODES) - mu * mu;
        float sc = gamma[t] * rsqrtf(var + 1e-5f);
        scale_s[t] = sc;
        shift_s[t] = beta[t] - mu * sc;
    }
    __syncthreads();

    int gr = r0 + sr; gr = gr < N_NODES ? gr : N_NODES - 1;
    const float* Xrow = X + (size_t)gr * 128;
    float4 xpreA = *(const float4*)(Xrow + 8 * sa);
    float4 xpreB = *(const float4*)(Xrow + 8 * sa + 4);
    if (apply_bn) {
        xpreA = bnelu4(xpreA, *(const float4*)(scale_s + 8 * sa), *(const float4*)(shift_s + 8 * sa), bscale);
        xpreB = bnelu4(xpreB, *(const float4*)(scale_s + 8 * sa + 4), *(const float4*)(shift_s + 8 * sa + 4), bscale);
    }
    float4 wpre[4];
#pragma unroll
    for (int q = 0; q < 4; ++q)
        wpre[q] = *(const float4*)(W + (size_t)(wk + 8 * q) * 128 + wc);

    float acc[4][8];
#pragma unroll
    for (int i = 0; i < 4; ++i)
#pragma unroll
        for (int c = 0; c < 8; ++c) acc[i][c] = 0.f;

    for (int step = 0; step < 4; ++step) {
        __syncthreads();
        Xs[8 * sa + 0][sr] = xpreA.x;
        Xs[8 * sa + 1][sr] = xpreA.y;
        Xs[8 * sa + 2][sr] = xpreA.z;
        Xs[8 * sa + 3][sr] = xpreA.w;
        Xs[8 * sa + 4][sr] = xpreB.x;
        Xs[8 * sa + 5][sr] = xpreB.y;
        Xs[8 * sa + 6][sr] = xpreB.z;
        Xs[8 * sa + 7][sr] = xpreB.w;
#pragma unroll
        for (int q = 0; q < 4; ++q)
            *(float4*)&Ws[wk + 8 * q][wc] = wpre[q];
        if (step < 3) {
            int k0 = (step + 1) * 32;
            xpreA = *(const float4*)(Xrow + k0 + 8 * sa);
            xpreB = *(const float4*)(Xrow + k0 + 8 * sa + 4);
            if (apply_bn) {
                xpreA = bnelu4(xpreA, *(const float4*)(scale_s + k0 + 8 * sa), *(const float4*)(shift_s + k0 + 8 * sa), bscale);
                xpreB = bnelu4(xpreB, *(const float4*)(scale_s + k0 + 8 * sa + 4), *(const float4*)(shift_s + k0 + 8 * sa + 4), bscale);
            }
#pragma unroll
            for (int q = 0; q < 4; ++q)
                wpre[q] = *(const float4*)(W + (size_t)(k0 + wk + 8 * q) * 128 + wc);
        }
        __syncthreads();
#pragma unroll
        for (int kk = 0; kk < 32; ++kk) {
            float4 xv = *(const float4*)&Xs[kk][4 * ty];
            float4 wv0 = *(const float4*)&Ws[kk][4 * tx];
            float4 wv1 = *(const float4*)&Ws[kk][4 * tx + 64];
            float xr[4] = {xv.x, xv.y, xv.z, xv.w};
            float wr[8] = {wv0.x, wv0.y, wv0.z, wv0.w, wv1.x, wv1.y, wv1.z, wv1.w};
#pragma unroll
            for (int i = 0; i < 4; ++i)
#pragma unroll
                for (int c = 0; c < 8; ++c)
                    acc[i][c] = fmaf(xr[i], wr[c], acc[i][c]);
        }
    }
    // epilogue: cols 4tx..4tx+3 (head h0 = tx>>3) and 64+4tx.. (head 2+h0)
    const int h0 = tx >> 3;
    float asv[8], adv[8];
#pragma unroll
    for (int c = 0; c < 8; ++c) {
        int col = (c < 4) ? (4 * tx + c) : (64 + 4 * tx + (c - 4));
        asv[c] = a_src[col];
        adv[c] = a_dst[col];
    }
#pragma unroll
    for (int i = 0; i < 4; ++i) {
        int r = r0 + 4 * ty + i;
        bool valid = r < N_NODES;
        if (valid) {
            uint2 pk0 = {pkh(acc[i][0], acc[i][1]), pkh(acc[i][2], acc[i][3])};
            uint2 pk1 = {pkh(acc[i][4], acc[i][5]), pkh(acc[i][6], acc[i][7])};
            *(uint2*)(Hout + (size_t)r * 64 + 2 * tx) = pk0;
            *(uint2*)(Hout + (size_t)r * 64 + 32 + 2 * tx) = pk1;
        }
        float ps0 = 0.f, pd0 = 0.f, ps1 = 0.f, pd1 = 0.f;
#pragma unroll
        for (int c = 0; c < 4; ++c) {
            ps0 = fmaf(acc[i][c], asv[c], ps0);
            pd0 = fmaf(acc[i][c], adv[c], pd0);
            ps1 = fmaf(acc[i][c + 4], asv[c + 4], ps1);
            pd1 = fmaf(acc[i][c + 4], adv[c + 4], pd1);
        }
#pragma unroll
        for (int off = 1; off < 8; off <<= 1) {
            ps0 += __shfl_xor(ps0, off);
            pd0 += __shfl_xor(pd0, off);
            ps1 += __shfl_xor(ps1, off);
            pd1 += __shfl_xor(pd1, off);
        }
        if (valid && (tx & 7) == 0) {
            als[r * 4 + h0] = ps0;
            ald[r * 4 + h0] = pd0;
            als[r * 4 + 2 + h0] = ps1;
            ald[r * 4 + 2 + h0] = pd1;
        }
    }
}

// ---------------- gemm40: [N,128]@[128,40] (+ fused BN-finalize/ELU) + als/ald, f16 h out ----------------
__global__ __launch_bounds__(256) void gemm40_kernel(
    const float* __restrict__ X, const float* __restrict__ W,
    const float* __restrict__ a_src, const float* __restrict__ a_dst,
    const float* __restrict__ sums, const float* __restrict__ sqs,
    const float* __restrict__ gamma, const float* __restrict__ beta, float bscale,
    unsigned short* __restrict__ Hout, float* __restrict__ als, float* __restrict__ ald) {
    __shared__ float Xs[64][36];
    __shared__ float Ws[40][36];
    __shared__ float scale_s[DHID], shift_s[DHID];
    const int t = threadIdx.x;
    const int tx = t & 7, ty = t >> 3;
    const int r0 = blockIdx.x * 64;
    const int sr = t >> 2, sa = t & 3;

    if (t < DHID) {
        float mu = sums[t] * (1.f / N_NODES);
        float var = sqs[t] * (1.f / N_NODES) - mu * mu;
        float sc = gamma[t] * rsqrtf(var + 1e-5f);
        scale_s[t] = sc;
        shift_s[t] = beta[t] - mu * sc;
    }
    __syncthreads();

    int gr = r0 + sr; gr = gr < N_NODES ? gr : N_NODES - 1;
    const float* Xrow = X + (size_t)gr * 128;
    float4 xpreA = bnelu4(*(const float4*)(Xrow + 8 * sa),
                          *(const float4*)(scale_s + 8 * sa), *(const float4*)(shift_s + 8 * sa), bscale);
    float4 xpreB = bnelu4(*(const float4*)(Xrow + 8 * sa + 4),
                          *(const float4*)(scale_s + 8 * sa + 4), *(const float4*)(shift_s + 8 * sa + 4), bscale);
    float wpre[5];
#pragma unroll
    for (int i = 0; i < 5; ++i) wpre[i] = W[t + 256 * i];

    float acc[2][5];
#pragma unroll
    for (int i = 0; i < 2; ++i)
#pragma unroll
        for (int j = 0; j < 5; ++j) acc[i][j] = 0.f;

    for (int step = 0; step < 4; ++step) {
        __syncthreads();
        *(float4*)&Xs[sr][8 * sa] = xpreA;
        *(float4*)&Xs[sr][8 * sa + 4] = xpreB;
#pragma unroll
        for (int i = 0; i < 5; ++i) {
            int idx = t + 256 * i;
            Ws[idx % 40][idx / 40] = wpre[i];
        }
        if (step < 3) {
            int k0 = (step + 1) * 32;
            xpreA = bnelu4(*(const float4*)(Xrow + k0 + 8 * sa),
                           *(const float4*)(scale_s + k0 + 8 * sa), *(const float4*)(shift_s + k0 + 8 * sa), bscale);
            xpreB = bnelu4(*(const float4*)(Xrow + k0 + 8 * sa + 4),
                           *(const float4*)(scale_s + k0 + 8 * sa + 4), *(const float4*)(shift_s + k0 + 8 * sa + 4), bscale);
#pragma unroll
            for (int i = 0; i < 5; ++i) wpre[i] = W[k0 * 40 + t + 256 * i];
        }
        __syncthreads();
#pragma unroll
        for (int kk4 = 0; kk4 < 8; ++kk4) {
            float4 xa = *(const float4*)&Xs[2 * ty][4 * kk4];
            float4 xb = *(const float4*)&Xs[2 * ty + 1][4 * kk4];
#pragma unroll
            for (int j = 0; j < 5; ++j) {
                float4 wv = *(const float4*)&Ws[tx + 8 * j][4 * kk4];
                acc[0][j] = fmaf(xa.x, wv.x, acc[0][j]);
                acc[0][j] = fmaf(xa.y, wv.y, acc[0][j]);
                acc[0][j] = fmaf(xa.z, wv.z, acc[0][j]);
                acc[0][j] = fmaf(xa.w, wv.w, acc[0][j]);
                acc[1][j] = fmaf(xb.x, wv.x, acc[1][j]);
                acc[1][j] = fmaf(xb.y, wv.y, acc[1][j]);
                acc[1][j] = fmaf(xb.z, wv.z, acc[1][j]);
                acc[1][j] = fmaf(xb.w, wv.w, acc[1][j]);
            }
        }
    }
    float asv[5], adv[5];
#pragma unroll
    for (int j = 0; j < 5; ++j) {
        asv[j] = a_src[tx + 8 * j];
        adv[j] = a_dst[tx + 8 * j];
    }
#pragma unroll
    for (int i = 0; i < 2; ++i) {
        int r = r0 + 2 * ty + i;
        bool valid = r < N_NODES;
        if (valid) {
#pragma unroll
            for (int j = 0; j < 5; ++j)
                Hout[(size_t)r * 40 + tx + 8 * j] = f2h(acc[i][j]);
        }
        float ps = 0.f, pd = 0.f;
#pragma unroll
        for (int j = 0; j < 5; ++j) {
            ps = fmaf(acc[i][j], asv[j], ps);
            pd = fmaf(acc[i][j], adv[j], pd);
        }
#pragma unroll
        for (int off = 1; off < 8; off <<= 1) {
            ps += __shfl_xor(ps, off);
            pd += __shfl_xor(pd, off);
        }
        if (valid && tx == 0) {
            als[r] = ps;
            ald[r] = pd;
        }
    }
}

// ---------------- agg128: one wave per node; 2-deep unrolled 8-edge gather ----------------
__global__ __launch_bounds__(256) void agg128_kernel(
    const int* __restrict__ row_ptr, const int* __restrict__ csr_src,
    const unsigned int* __restrict__ Ht, const float* __restrict__ als, const float* __restrict__ ald,
    const float* __restrict__ bias, float* __restrict__ out) {
    __shared__ float s_p[4][256];
    __shared__ int s_u[4][64];
    int v = (blockIdx.x * blockDim.x + threadIdx.x) >> 6;
    v = __builtin_amdgcn_readfirstlane(v);
    int lane = threadIdx.x & 63;
    int wslot = threadIdx.x >> 6;
    if (v >= N_NODES) return;
    int beg = row_ptr[v], end = row_ptr[v + 1];
    float4 ad4 = *(const float4*)(ald + (size_t)v * 4);
    const int g = lane >> 4;
    const int li = lane & 15;
    const int hh = li >> 2;
    float tsum = 0.f;
    float acc[8];
#pragma unroll
    for (int j = 0; j < 8; ++j) acc[j] = 0.f;

    for (int cbeg = beg; cbeg < end; cbeg += 64) {
        int cnt = min(64, end - cbeg);
        bool act = lane < cnt;
        int u = act ? csr_src[cbeg + lane] : 0;
        float p0, p1, p2, p3;
        if (act) {
            float4 s4 = *(const float4*)(als + (size_t)u * 4);
            p0 = __expf(lrelu(s4.x + ad4.x));
            p1 = __expf(lrelu(s4.y + ad4.y));
            p2 = __expf(lrelu(s4.z + ad4.z));
            p3 = __expf(lrelu(s4.w + ad4.w));
        } else {
            p0 = p1 = p2 = p3 = 0.f;
        }
        s_u[wslot][lane] = u;
        float4 pv = {p0, p1, p2, p3};
        *(float4*)&s_p[wslot][lane * 4] = pv;
        for (int i = 0; i < cnt; i += 8) {
            int ea = i + g;
            int eb = i + 4 + g;
            int ua = s_u[wslot][ea];
            int ub = s_u[wslot][eb];
            float pa = s_p[wslot][ea * 4 + hh];
            float pb = s_p[wslot][eb * 4 + hh];
            uint4 wa = *(const uint4*)(Ht + (size_t)ua * 64 + li * 4);
            uint4 wb = *(const uint4*)(Ht + (size_t)ub * 64 + li * 4);
            tsum += pa + pb;
            fma8(acc, wa, pa);
            fma8(acc, wb, pb);
        }
    }
#pragma unroll
    for (int j = 0; j < 8; ++j) {
        acc[j] += __shfl_xor(acc[j], 16);
        acc[j] += __shfl_xor(acc[j], 32);
    }
    tsum += __shfl_xor(tsum, 16);
    tsum += __shfl_xor(tsum, 32);
    float inv = 1.f / (tsum + 1e-16f);
    if (g == 0) {
        float4 b0 = *(const float4*)(bias + 8 * li);
        float4 b1 = *(const float4*)(bias + 8 * li + 4);
        float4 o0 = {acc[0] * inv + b0.x, acc[1] * inv + b0.y, acc[2] * inv + b0.z, acc[3] * inv + b0.w};
        float4 o1 = {acc[4] * inv + b1.x, acc[5] * inv + b1.y, acc[6] * inv + b1.z, acc[7] * inv + b1.w};
        *(float4*)(out + (size_t)v * DHID + 8 * li) = o0;
        *(float4*)(out + (size_t)v * DHID + 8 * li + 4) = o1;
    }
}

// ---------------- agg40: one wave per node; 12-edge-parallel uint4 gather + log_softmax ----------------
__global__ __launch_bounds__(256) void agg40_kernel(
    const int* __restrict__ row_ptr, const int* __restrict__ csr_src,
    const uint4* __restrict__ Ht4, const float* __restrict__ als, const float* __restrict__ ald,
    const float* __restrict__ bias, float* __restrict__ out) {
    __shared__ float s_p[4][76];
    __shared__ int s_u[4][76];
    __shared__ float s_red[4][12][41];
    int v = (blockIdx.x * blockDim.x + threadIdx.x) >> 6;
    v = __builtin_amdgcn_readfirstlane(v);
    int lane = threadIdx.x & 63;
    int wslot = threadIdx.x >> 6;
    if (v >= N_NODES) return;
    int beg = row_ptr[v], end = row_ptr[v + 1];
    float adv = ald[v];
    const int g = lane / 5;
    const int li = lane - g * 5;
    const bool gact = lane < 60;
    if (lane < 12) { s_u[wslot][64 + lane] = 0; s_p[wslot][64 + lane] = 0.f; }
    float tsum = 0.f;
    float a[8];
#pragma unroll
    for (int j = 0; j < 8; ++j) a[j] = 0.f;

    for (int cbeg = beg; cbeg < end; cbeg += 64) {
        int cnt = min(64, end - cbeg);
        bool act = lane < cnt;
        int u = act ? csr_src[cbeg + lane] : 0;
        float p = act ? __expf(lrelu(als[u] + adv)) : 0.f;
        s_u[wslot][lane] = u;
        s_p[wslot][lane] = p;
        for (int i = 0; i < cnt; i += 12) {
            int e = i + g;
            int uu = s_u[wslot][e];
            float pp = s_p[wslot][e];
            uint4 w = {0u, 0u, 0u, 0u};
            if (gact) w = Ht4[(size_t)uu * 5 + li];
            if (gact) tsum += pp;
            fma8(a, w, pp);
        }
    }
    if (gact) {
#pragma unroll
        for (int j = 0; j < 8; ++j) s_red[wslot][g][li * 8 + j] = a[j];
        if (li == 0) s_red[wslot][g][40] = tsum;
    }
    bool fown = lane < DOUT;
    float accf = 0.f, T = 0.f;
#pragma unroll
    for (int g2 = 0; g2 < 12; ++g2) {
        if (fown) accf += s_red[wslot][g2][lane];
        T += s_red[wslot][g2][40];
    }
    float inv = 1.f / (T + 1e-16f);
    float z = fown ? (accf * inv + bias[lane]) : -1e30f;
    float zm = z;
#pragma unroll
    for (int off = 1; off < 64; off <<= 1) zm = fmaxf(zm, __shfl_xor(zm, off));
    float se = fown ? __expf(z - zm) : 0.f;
#pragma unroll
    for (int off = 1; off < 64; off <<= 1) se += __shfl_xor(se, off);
    float ls = zm + logf(se);
    if (fown) out[(size_t)v * DOUT + lane] = z - ls;
}

// ---------------- batch norm stats (float4-vectorized) ----------------
__global__ __launch_bounds__(256) void bn_stats_kernel(const float* __restrict__ X,
                                                       float* __restrict__ sums, float* __restrict__ sqs) {
    const int t = threadIdx.x;
    const int tid = blockIdx.x * 256 + t;
    const float4* X4 = (const float4*)X;
    float4 s = {0.f, 0.f, 0.f, 0.f}, q = {0.f, 0.f, 0.f, 0.f};
    for (int i = tid; i < N_NODES * 32; i += 500 * 256) {
        float4 vv = X4[i];
        s.x += vv.x; s.y += vv.y; s.z += vv.z; s.w += vv.w;
        q.x += vv.x * vv.x; q.y += vv.y * vv.y; q.z += vv.z * vv.z; q.w += vv.w * vv.w;
    }
    __shared__ float ls[1024], lq[1024];
    *(float4*)&ls[t * 4] = s;
    *(float4*)&lq[t * 4] = q;
    __syncthreads();
    if (t < 128) {
        int c4 = t >> 2, j = t & 3;
        float S = 0.f, Q = 0.f;
#pragma unroll
        for (int k = 0; k < 8; ++k) {
            S += ls[(c4 + 32 * k) * 4 + j];
            Q += lq[(c4 + 32 * k) * 4 + j];
        }
        atomicAdd(&sums[t], S);
        atomicAdd(&sqs[t], Q);
    }
}

// ---------------- launch ----------------
extern "C" void kernel_launch(void* const* d_in, const int* in_sizes, int n_in,
                              void* d_out, int out_size, void* d_ws, size_t ws_size,
                              hipStream_t stream) {
    (void)in_sizes; (void)n_in; (void)out_size; (void)ws_size;
    const float* x = (const float*)d_in[0];
    const int* ei = (const int*)d_in[1];
    const float* W0 = (const float*)d_in[2];
    const float* as0 = (const float*)d_in[3];
    const float* ad0 = (const float*)d_in[4];
    const float* b0 = (const float*)d_in[5];
    const float* W1 = (const float*)d_in[6];
    const float* as1 = (const float*)d_in[7];
    const float* ad1 = (const float*)d_in[8];
    const float* b1 = (const float*)d_in[9];
    const float* W2 = (const float*)d_in[10];
    const float* as2 = (const float*)d_in[11];
    const float* ad2 = (const float*)d_in[12];
    const float* b2 = (const float*)d_in[13];
    const float* g_bn0 = (const float*)d_in[14];
    const float* be_bn0 = (const float*)d_in[15];
    const float* g_bn1 = (const float*)d_in[16];
    const float* be_bn1 = (const float*)d_in[17];
    float* out = (float*)d_out;

    const int* srcv = ei;
    const int* dstv = ei + N_EDGES;

    char* p = (char*)d_ws;
    auto carve = [&](size_t bytes) {
        char* q = p;
        p += (bytes + 255) & ~(size_t)255;
        return q;
    };
    unsigned int* h_bf = (unsigned int*)carve((size_t)N_NODES * 64 * 4);  // f16 h (also as [N,40] rows)
    float* agg   = (float*)carve((size_t)N_NODES * DHID * 4);
    float* als   = (float*)carve((size_t)N_NODES * NH * 4);
    float* ald   = (float*)carve((size_t)N_NODES * NH * 4);
    int* row_ptr = (int*)carve((size_t)(N_NODES + 1) * 4);
    int* csr_src = (int*)carve((size_t)N_EDGES * 4);
    unsigned* part = (unsigned*)carve((size_t)N_EDGES * 4);
    int* bhist   = (int*)carve((PB + 512) * 4);
    float* sums0 = (float*)(bhist + PB);
    float* sqs0  = sums0 + 128;
    float* sums1 = sqs0 + 128;
    float* sqs1  = sums1 + 128;
    int* bucket_base = (int*)carve((PB + 1) * 4);
    int* cursor  = (int*)carve(PB * 4);

    const float bs0 = 1.0f + 1.0f / 25.001f;
    const float bs1 = 1.0f + 0.5f / 25.001f;

    const int RT64 = (N_NODES + 63) / 64;      // 782
    const int G128B = RT64;                    // 782 (full 128-col tile per block)
    const int G40B = RT64;                     // 782
    const int AB = (N_NODES * 64 + 255) / 256; // 12500
    const int PARTB = (N_EDGES + 4095) / 4096; // 196

    // ---- bucketed CSR build ----
    hipMemsetAsync(bhist, 0, (PB + 512) * 4, stream);
    bucket_hist_kernel<<<400, 256, 0, stream>>>(dstv, bhist);
    bucket_scan_kernel<<<1, PB, 0, stream>>>(bhist, bucket_base, cursor);
    partition_kernel<<<PARTB, 256, 0, stream>>>(srcv, dstv, cursor, part);
    bucket_csr_kernel<<<PB, 256, 0, stream>>>(part, bucket_base, row_ptr, csr_src);

    // ---- layer 0 ----
    gemm128_kernel<<<G128B, 256, 0, stream>>>(x, W0, as0, ad0, nullptr, nullptr, nullptr, nullptr, 1.f, 0, h_bf, als, ald);
    agg128_kernel<<<AB, 256, 0, stream>>>(row_ptr, csr_src, h_bf, als, ald, b0, agg);
    bn_stats_kernel<<<500, 256, 0, stream>>>(agg, sums0, sqs0);

    // ---- layer 1 (BN0 finalize+ELU fused into gemm) ----
    gemm128_kernel<<<G128B, 256, 0, stream>>>(agg, W1, as1, ad1, sums0, sqs0, g_bn0, be_bn0, bs0, 1, h_bf, als, ald);
    agg128_kernel<<<AB, 256, 0, stream>>>(row_ptr, csr_src, h_bf, als, ald, b1, agg);
    bn_stats_kernel<<<500, 256, 0, stream>>>(agg, sums1, sqs1);

    // ---- layer 2 (BN1 finalize+ELU fused) + log_softmax ----
    gemm40_kernel<<<G40B, 256, 0, stream>>>(agg, W2, as2, ad2, sums1, sqs1, g_bn1, be_bn1, bs1, (unsigned short*)h_bf, als, ald);
    agg40_kernel<<<AB, 256, 0, stream>>>(row_ptr, csr_src, (const uint4*)h_bf, als, ald, b2, out);
}

// Round 16
// 270.239 us; speedup vs baseline: 1.0369x; 1.0369x over previous
//
#include <hip/hip_runtime.h>
#include <math.h>

#define N_NODES 50000
#define N_EDGES 800000
#define DIN 128
#define DHID 128   /* H*HID */
#define NH 4
#define HID 32
#define DOUT 40

#define PB 128      /* dst buckets */
#define NPB 391     /* nodes per bucket: 391*128 = 50048 >= 50000 */

typedef __fp16 fp16x2 __attribute__((ext_vector_type(2)));

static __device__ __forceinline__ float lrelu(float x) { return x > 0.f ? x : 0.2f * x; }

static __device__ __forceinline__ unsigned int pkh(float a, float b) {
    union { fp16x2 h2; unsigned int u; } cv;
    cv.h2 = __builtin_amdgcn_cvt_pkrtz(a, b);
    return cv.u;
}
static __device__ __forceinline__ unsigned short f2h(float a) {
    union { _Float16 h; unsigned short s; } cv;
    cv.h = (_Float16)a;
    return cv.s;
}

// acc[0..7] += p * f16x8(w)  — unpack via f16->f32 (fuses to v_fma_mix)
static __device__ __forceinline__ void fma8(float* acc, uint4 w, float p) {
    union { unsigned int u; _Float16 h[2]; } c0, c1, c2, c3;
    c0.u = w.x; c1.u = w.y; c2.u = w.z; c3.u = w.w;
    acc[0] = fmaf((float)c0.h[0], p, acc[0]);
    acc[1] = fmaf((float)c0.h[1], p, acc[1]);
    acc[2] = fmaf((float)c1.h[0], p, acc[2]);
    acc[3] = fmaf((float)c1.h[1], p, acc[3]);
    acc[4] = fmaf((float)c2.h[0], p, acc[4]);
    acc[5] = fmaf((float)c2.h[1], p, acc[5]);
    acc[6] = fmaf((float)c3.h[0], p, acc[6]);
    acc[7] = fmaf((float)c3.h[1], p, acc[7]);
}

static __device__ __forceinline__ float4 bnelu4(float4 x, float4 sc, float4 sh, float bs) {
    float y0 = fmaf(x.x, sc.x, sh.x);
    float y1 = fmaf(x.y, sc.y, sh.y);
    float y2 = fmaf(x.z, sc.z, sh.z);
    float y3 = fmaf(x.w, sc.w, sh.w);
    y0 = (y0 > 0.f ? y0 : __expf(y0) - 1.f) * bs;
    y1 = (y1 > 0.f ? y1 : __expf(y1) - 1.f) * bs;
    y2 = (y2 > 0.f ? y2 : __expf(y2) - 1.f) * bs;
    y3 = (y3 > 0.f ? y3 : __expf(y3) - 1.f) * bs;
    return {y0, y1, y2, y3};
}

// ================= bucketed CSR build (XCD-local writes) =================
__global__ __launch_bounds__(256) void bucket_hist_kernel(const int* __restrict__ dstv, int* __restrict__ bhist) {
    __shared__ int h[PB];
    if (threadIdx.x < PB) h[threadIdx.x] = 0;
    __syncthreads();
    for (int i = blockIdx.x * blockDim.x + threadIdx.x; i < N_EDGES; i += gridDim.x * blockDim.x)
        atomicAdd(&h[(unsigned)dstv[i] / NPB], 1);
    __syncthreads();
    if (threadIdx.x < PB) atomicAdd(&bhist[threadIdx.x], h[threadIdx.x]);
}

__global__ __launch_bounds__(128) void bucket_scan_kernel(const int* __restrict__ bhist,
                                                          int* __restrict__ bucket_base, int* __restrict__ cursor) {
    __shared__ int sA[PB], sB[PB];
    int t = threadIdx.x;
    sA[t] = bhist[t];
    __syncthreads();
    int* s = sA; int* d2 = sB;
    for (int off = 1; off < PB; off <<= 1) {
        d2[t] = s[t] + (t >= off ? s[t - off] : 0);
        __syncthreads();
        int* tmp = s; s = d2; d2 = tmp;
    }
    int excl = s[t] - bhist[t];
    bucket_base[t] = excl;
    cursor[t] = excl;
    if (t == PB - 1) bucket_base[PB] = s[t];
}

// records packed as (src<<16)|dst — both < 65536
__global__ __launch_bounds__(256) void partition_kernel(const int* __restrict__ srcv, const int* __restrict__ dstv,
                                                        int* __restrict__ cursor, unsigned* __restrict__ part) {
    __shared__ unsigned rec[2048];
    __shared__ int cnt[PB], lofs[PB], gbase[PB];
    __shared__ int sA[PB], sB[PB];
    __shared__ int tot_s;
    const int t = threadIdx.x;
    const int base0 = blockIdx.x * 4096;
    for (int round = 0; round < 2; ++round) {
        int rbase = base0 + round * 2048;
        if (t < PB) cnt[t] = 0;
        __syncthreads();
        int myb[8]; int myr[8]; unsigned myrec[8];
#pragma unroll
        for (int i = 0; i < 8; ++i) {
            int e = rbase + i * 256 + t;
            bool valid = e < N_EDGES;
            int sv = valid ? srcv[e] : 0;
            int dv = valid ? dstv[e] : 0;
            myrec[i] = ((unsigned)sv << 16) | (unsigned)dv;
            int b = (unsigned)dv / NPB;
            myb[i] = valid ? b : -1;
            myr[i] = valid ? atomicAdd(&cnt[b], 1) : 0;
        }
        __syncthreads();
        if (t < PB) sA[t] = cnt[t];
        __syncthreads();
        int* s = sA; int* d2 = sB;
        for (int off = 1; off < PB; off <<= 1) {
            if (t < PB) d2[t] = s[t] + (t >= off ? s[t - off] : 0);
            __syncthreads();
            int* tmp = s; s = d2; d2 = tmp;
        }
        if (t < PB) {
            int c = cnt[t];
            lofs[t] = s[t] - c;
            gbase[t] = c > 0 ? atomicAdd(&cursor[t], c) : 0;
            if (t == PB - 1) tot_s = s[t];
        }
        __syncthreads();
#pragma unroll
        for (int i = 0; i < 8; ++i)
            if (myb[i] >= 0) rec[lofs[myb[i]] + myr[i]] = myrec[i];
        __syncthreads();
        int tot = tot_s;
#pragma unroll
        for (int i = 0; i < 8; ++i) {
            int lp = i * 256 + t;
            if (lp < tot) {
                unsigned r = rec[lp];
                int b = (r & 0xFFFFu) / NPB;
                part[gbase[b] + (lp - lofs[b])] = r;
            }
        }
        __syncthreads();
    }
}

__global__ __launch_bounds__(256) void bucket_csr_kernel(const unsigned* __restrict__ part, const int* __restrict__ bucket_base,
                                                         int* __restrict__ row_ptr, int* __restrict__ csr_src) {
    __shared__ int hist[512], sA[512], sB[512], cur[NPB];
    const int b = blockIdx.x, t = threadIdx.x;
    const int base = bucket_base[b];
    const int n = bucket_base[b + 1] - base;
    hist[t] = 0; hist[t + 256] = 0;
    __syncthreads();
    for (int i = t; i < n; i += 256)
        atomicAdd(&hist[(part[base + i] & 0xFFFFu) - b * NPB], 1);
    __syncthreads();
    sA[t] = hist[t]; sA[t + 256] = hist[t + 256];
    __syncthreads();
    int* s = sA; int* d2 = sB;
    for (int off = 1; off < 512; off <<= 1) {
        d2[t] = s[t] + (t >= off ? s[t - off] : 0);
        int u = t + 256;
        d2[u] = s[u] + (u >= off ? s[u - off] : 0);
        __syncthreads();
        int* tmp = s; s = d2; d2 = tmp;
    }
    for (int j = t; j < NPB; j += 256) {
        int node = b * NPB + j;
        int excl = s[j] - hist[j];
        if (node < N_NODES) row_ptr[node] = base + excl;
        cur[j] = excl;
    }
    if (b == PB - 1 && t == 0) row_ptr[N_NODES] = N_EDGES;
    __syncthreads();
    for (int i = t; i < n; i += 256) {
        unsigned r = part[base + i];
        int loc = (int)(r & 0xFFFFu) - b * NPB;
        int p = atomicAdd(&cur[loc], 1);
        csr_src[base + p] = (int)(r >> 16);
    }
}

// ---------------- gemm128: 64x64 tile per block (+ fused BN-finalize/ELU) + als/ald epilogue ----------------
__global__ __launch_bounds__(256) void gemm128_kernel(
    const float* __restrict__ X, const float* __restrict__ W,
    const float* __restrict__ a_src, const float* __restrict__ a_dst,
    const float* __restrict__ sums, const float* __restrict__ sqs,
    const float* __restrict__ gamma, const float* __restrict__ beta, float bscale, int apply_bn,
    unsigned int* __restrict__ Hout, float* __restrict__ als, float* __restrict__ ald) {
    __shared__ float Xs[32][68];
    __shared__ float Ws[32][64];
    __shared__ float scale_s[DHID], shift_s[DHID];
    const int t = threadIdx.x;
    const int tx = t & 15, ty = t >> 4;
    const int r0 = (blockIdx.x >> 1) * 64;
    const int c0 = (blockIdx.x & 1) * 64;
    const int sr = t >> 2, sa = t & 3;
    const int wk = t >> 4, wc = (t & 15) * 4;

    if (apply_bn && t < DHID) {
        float mu = sums[t] * (1.f / N_NODES);
        float var = sqs[t] * (1.f / N_NODES) - mu * mu;
        float sc = gamma[t] * rsqrtf(var + 1e-5f);
        scale_s[t] = sc;
        shift_s[t] = beta[t] - mu * sc;
    }
    __syncthreads();

    int gr = r0 + sr; gr = gr < N_NODES ? gr : N_NODES - 1;
    const float* Xrow = X + (size_t)gr * 128;
    float4 xpreA = *(const float4*)(Xrow + 8 * sa);
    float4 xpreB = *(const float4*)(Xrow + 8 * sa + 4);
    if (apply_bn) {
        xpreA = bnelu4(xpreA, *(const float4*)(scale_s + 8 * sa), *(const float4*)(shift_s + 8 * sa), bscale);
        xpreB = bnelu4(xpreB, *(const float4*)(scale_s + 8 * sa + 4), *(const float4*)(shift_s + 8 * sa + 4), bscale);
    }
    float4 wpreA = *(const float4*)(W + (size_t)wk * 128 + c0 + wc);
    float4 wpreB = *(const float4*)(W + (size_t)(wk + 16) * 128 + c0 + wc);

    float acc[4][4];
#pragma unroll
    for (int i = 0; i < 4; ++i)
#pragma unroll
        for (int c = 0; c < 4; ++c) acc[i][c] = 0.f;

    for (int step = 0; step < 4; ++step) {
        __syncthreads();
        Xs[8 * sa + 0][sr] = xpreA.x;
        Xs[8 * sa + 1][sr] = xpreA.y;
        Xs[8 * sa + 2][sr] = xpreA.z;
        Xs[8 * sa + 3][sr] = xpreA.w;
        Xs[8 * sa + 4][sr] = xpreB.x;
        Xs[8 * sa + 5][sr] = xpreB.y;
        Xs[8 * sa + 6][sr] = xpreB.z;
        Xs[8 * sa + 7][sr] = xpreB.w;
        *(float4*)&Ws[wk][wc] = wpreA;
        *(float4*)&Ws[wk + 16][wc] = wpreB;
        if (step < 3) {
            int k0 = (step + 1) * 32;
            xpreA = *(const float4*)(Xrow + k0 + 8 * sa);
            xpreB = *(const float4*)(Xrow + k0 + 8 * sa + 4);
            if (apply_bn) {
                xpreA = bnelu4(xpreA, *(const float4*)(scale_s + k0 + 8 * sa), *(const float4*)(shift_s + k0 + 8 * sa), bscale);
                xpreB = bnelu4(xpreB, *(const float4*)(scale_s + k0 + 8 * sa + 4), *(const float4*)(shift_s + k0 + 8 * sa + 4), bscale);
            }
            wpreA = *(const float4*)(W + (size_t)(k0 + wk) * 128 + c0 + wc);
            wpreB = *(const float4*)(W + (size_t)(k0 + wk + 16) * 128 + c0 + wc);
        }
        __syncthreads();
#pragma unroll
        for (int kk = 0; kk < 32; ++kk) {
            float4 xv = *(const float4*)&Xs[kk][4 * ty];
            float4 wv = *(const float4*)&Ws[kk][4 * tx];
            float xr[4] = {xv.x, xv.y, xv.z, xv.w};
            float wr[4] = {wv.x, wv.y, wv.z, wv.w};
#pragma unroll
            for (int i = 0; i < 4; ++i)
#pragma unroll
                for (int c = 0; c < 4; ++c)
                    acc[i][c] = fmaf(xr[i], wr[c], acc[i][c]);
        }
    }
    const int head = (c0 >> 5) + (tx >> 3);
    float asv[4], adv[4];
#pragma unroll
    for (int c = 0; c < 4; ++c) {
        asv[c] = a_src[(head & 1) * 32 + (4 * tx + c) % 32 + (head >> 1) * 64];
        adv[c] = a_dst[(head & 1) * 32 + (4 * tx + c) % 32 + (head >> 1) * 64];
    }
#pragma unroll
    for (int i = 0; i < 4; ++i) {
        int r = r0 + 4 * ty + i;
        bool valid = r < N_NODES;
        if (valid) {
            uint2 pk = {pkh(acc[i][0], acc[i][1]), pkh(acc[i][2], acc[i][3])};
            *(uint2*)(Hout + (size_t)r * 64 + (c0 >> 1) + 2 * tx) = pk;
        }
        float ps = 0.f, pd = 0.f;
#pragma unroll
        for (int c = 0; c < 4; ++c) {
            ps = fmaf(acc[i][c], asv[c], ps);
            pd = fmaf(acc[i][c], adv[c], pd);
        }
#pragma unroll
        for (int off = 1; off < 8; off <<= 1) {
            ps += __shfl_xor(ps, off);
            pd += __shfl_xor(pd, off);
        }
        if (valid && (tx & 7) == 0) {
            als[r * 4 + head] = ps;
            ald[r * 4 + head] = pd;
        }
    }
}

// ---------------- gemm40: [N,128]@[128,40] (+ fused BN-finalize/ELU) + als/ald, f16 h out ----------------
__global__ __launch_bounds__(256) void gemm40_kernel(
    const float* __restrict__ X, const float* __restrict__ W,
    const float* __restrict__ a_src, const float* __restrict__ a_dst,
    const float* __restrict__ sums, const float* __restrict__ sqs,
    const float* __restrict__ gamma, const float* __restrict__ beta, float bscale,
    unsigned short* __restrict__ Hout, float* __restrict__ als, float* __restrict__ ald) {
    __shared__ float Xs[64][36];
    __shared__ float Ws[40][36];
    __shared__ float scale_s[DHID], shift_s[DHID];
    const int t = threadIdx.x;
    const int tx = t & 7, ty = t >> 3;
    const int r0 = blockIdx.x * 64;
    const int sr = t >> 2, sa = t & 3;

    if (t < DHID) {
        float mu = sums[t] * (1.f / N_NODES);
        float var = sqs[t] * (1.f / N_NODES) - mu * mu;
        float sc = gamma[t] * rsqrtf(var + 1e-5f);
        scale_s[t] = sc;
        shift_s[t] = beta[t] - mu * sc;
    }
    __syncthreads();

    int gr = r0 + sr; gr = gr < N_NODES ? gr : N_NODES - 1;
    const float* Xrow = X + (size_t)gr * 128;
    float4 xpreA = bnelu4(*(const float4*)(Xrow + 8 * sa),
                          *(const float4*)(scale_s + 8 * sa), *(const float4*)(shift_s + 8 * sa), bscale);
    float4 xpreB = bnelu4(*(const float4*)(Xrow + 8 * sa + 4),
                          *(const float4*)(scale_s + 8 * sa + 4), *(const float4*)(shift_s + 8 * sa + 4), bscale);
    float wpre[5];
#pragma unroll
    for (int i = 0; i < 5; ++i) wpre[i] = W[t + 256 * i];

    float acc[2][5];
#pragma unroll
    for (int i = 0; i < 2; ++i)
#pragma unroll
        for (int j = 0; j < 5; ++j) acc[i][j] = 0.f;

    for (int step = 0; step < 4; ++step) {
        __syncthreads();
        *(float4*)&Xs[sr][8 * sa] = xpreA;
        *(float4*)&Xs[sr][8 * sa + 4] = xpreB;
#pragma unroll
        for (int i = 0; i < 5; ++i) {
            int idx = t + 256 * i;
            Ws[idx % 40][idx / 40] = wpre[i];
        }
        if (step < 3) {
            int k0 = (step + 1) * 32;
            xpreA = bnelu4(*(const float4*)(Xrow + k0 + 8 * sa),
                           *(const float4*)(scale_s + k0 + 8 * sa), *(const float4*)(shift_s + k0 + 8 * sa), bscale);
            xpreB = bnelu4(*(const float4*)(Xrow + k0 + 8 * sa + 4),
                           *(const float4*)(scale_s + k0 + 8 * sa + 4), *(const float4*)(shift_s + k0 + 8 * sa + 4), bscale);
#pragma unroll
            for (int i = 0; i < 5; ++i) wpre[i] = W[k0 * 40 + t + 256 * i];
        }
        __syncthreads();
#pragma unroll
        for (int kk4 = 0; kk4 < 8; ++kk4) {
            float4 xa = *(const float4*)&Xs[2 * ty][4 * kk4];
            float4 xb = *(const float4*)&Xs[2 * ty + 1][4 * kk4];
#pragma unroll
            for (int j = 0; j < 5; ++j) {
                float4 wv = *(const float4*)&Ws[tx + 8 * j][4 * kk4];
                acc[0][j] = fmaf(xa.x, wv.x, acc[0][j]);
                acc[0][j] = fmaf(xa.y, wv.y, acc[0][j]);
                acc[0][j] = fmaf(xa.z, wv.z, acc[0][j]);
                acc[0][j] = fmaf(xa.w, wv.w, acc[0][j]);
                acc[1][j] = fmaf(xb.x, wv.x, acc[1][j]);
                acc[1][j] = fmaf(xb.y, wv.y, acc[1][j]);
                acc[1][j] = fmaf(xb.z, wv.z, acc[1][j]);
                acc[1][j] = fmaf(xb.w, wv.w, acc[1][j]);
            }
        }
    }
    float asv[5], adv[5];
#pragma unroll
    for (int j = 0; j < 5; ++j) {
        asv[j] = a_src[tx + 8 * j];
        adv[j] = a_dst[tx + 8 * j];
    }
#pragma unroll
    for (int i = 0; i < 2; ++i) {
        int r = r0 + 2 * ty + i;
        bool valid = r < N_NODES;
        if (valid) {
#pragma unroll
            for (int j = 0; j < 5; ++j)
                Hout[(size_t)r * 40 + tx + 8 * j] = f2h(acc[i][j]);
        }
        float ps = 0.f, pd = 0.f;
#pragma unroll
        for (int j = 0; j < 5; ++j) {
            ps = fmaf(acc[i][j], asv[j], ps);
            pd = fmaf(acc[i][j], adv[j], pd);
        }
#pragma unroll
        for (int off = 1; off < 8; off <<= 1) {
            ps += __shfl_xor(ps, off);
            pd += __shfl_xor(pd, off);
        }
        if (valid && tx == 0) {
            als[r] = ps;
            ald[r] = pd;
        }
    }
}

// ---------------- agg128: one wave per node; 2-deep unrolled 8-edge gather ----------------
__global__ __launch_bounds__(256) void agg128_kernel(
    const int* __restrict__ row_ptr, const int* __restrict__ csr_src,
    const unsigned int* __restrict__ Ht, const float* __restrict__ als, const float* __restrict__ ald,
    const float* __restrict__ bias, float* __restrict__ out) {
    __shared__ float s_p[4][256];
    __shared__ int s_u[4][64];
    int v = (blockIdx.x * blockDim.x + threadIdx.x) >> 6;
    v = __builtin_amdgcn_readfirstlane(v);
    int lane = threadIdx.x & 63;
    int wslot = threadIdx.x >> 6;
    if (v >= N_NODES) return;
    int beg = row_ptr[v], end = row_ptr[v + 1];
    float4 ad4 = *(const float4*)(ald + (size_t)v * 4);
    const int g = lane >> 4;
    const int li = lane & 15;
    const int hh = li >> 2;
    float tsum = 0.f;
    float acc[8];
#pragma unroll
    for (int j = 0; j < 8; ++j) acc[j] = 0.f;

    for (int cbeg = beg; cbeg < end; cbeg += 64) {
        int cnt = min(64, end - cbeg);
        bool act = lane < cnt;
        int u = act ? csr_src[cbeg + lane] : 0;
        float p0, p1, p2, p3;
        if (act) {
            float4 s4 = *(const float4*)(als + (size_t)u * 4);
            p0 = __expf(lrelu(s4.x + ad4.x));
            p1 = __expf(lrelu(s4.y + ad4.y));
            p2 = __expf(lrelu(s4.z + ad4.z));
            p3 = __expf(lrelu(s4.w + ad4.w));
        } else {
            p0 = p1 = p2 = p3 = 0.f;
        }
        s_u[wslot][lane] = u;
        float4 pv = {p0, p1, p2, p3};
        *(float4*)&s_p[wslot][lane * 4] = pv;
        for (int i = 0; i < cnt; i += 8) {
            int ea = i + g;
            int eb = i + 4 + g;
            int ua = s_u[wslot][ea];
            int ub = s_u[wslot][eb];
            float pa = s_p[wslot][ea * 4 + hh];
            float pb = s_p[wslot][eb * 4 + hh];
            uint4 wa = *(const uint4*)(Ht + (size_t)ua * 64 + li * 4);
            uint4 wb = *(const uint4*)(Ht + (size_t)ub * 64 + li * 4);
            tsum += pa + pb;
            fma8(acc, wa, pa);
            fma8(acc, wb, pb);
        }
    }
#pragma unroll
    for (int j = 0; j < 8; ++j) {
        acc[j] += __shfl_xor(acc[j], 16);
        acc[j] += __shfl_xor(acc[j], 32);
    }
    tsum += __shfl_xor(tsum, 16);
    tsum += __shfl_xor(tsum, 32);
    float inv = 1.f / (tsum + 1e-16f);
    if (g == 0) {
        float4 b0 = *(const float4*)(bias + 8 * li);
        float4 b1 = *(const float4*)(bias + 8 * li + 4);
        float4 o0 = {acc[0] * inv + b0.x, acc[1] * inv + b0.y, acc[2] * inv + b0.z, acc[3] * inv + b0.w};
        float4 o1 = {acc[4] * inv + b1.x, acc[5] * inv + b1.y, acc[6] * inv + b1.z, acc[7] * inv + b1.w};
        *(float4*)(out + (size_t)v * DHID + 8 * li) = o0;
        *(float4*)(out + (size_t)v * DHID + 8 * li + 4) = o1;
    }
}

// ---------------- agg40: one wave per node; 12-edge-parallel uint4 gather + log_softmax ----------------
__global__ __launch_bounds__(256) void agg40_kernel(
    const int* __restrict__ row_ptr, const int* __restrict__ csr_src,
    const uint4* __restrict__ Ht4, const float* __restrict__ als, const float* __restrict__ ald,
    const float* __restrict__ bias, float* __restrict__ out) {
    __shared__ float s_p[4][76];
    __shared__ int s_u[4][76];
    __shared__ float s_red[4][12][41];
    int v = (blockIdx.x * blockDim.x + threadIdx.x) >> 6;
    v = __builtin_amdgcn_readfirstlane(v);
    int lane = threadIdx.x & 63;
    int wslot = threadIdx.x >> 6;
    if (v >= N_NODES) return;
    int beg = row_ptr[v], end = row_ptr[v + 1];
    float adv = ald[v];
    const int g = lane / 5;
    const int li = lane - g * 5;
    const bool gact = lane < 60;
    if (lane < 12) { s_u[wslot][64 + lane] = 0; s_p[wslot][64 + lane] = 0.f; }
    float tsum = 0.f;
    float a[8];
#pragma unroll
    for (int j = 0; j < 8; ++j) a[j] = 0.f;

    for (int cbeg = beg; cbeg < end; cbeg += 64) {
        int cnt = min(64, end - cbeg);
        bool act = lane < cnt;
        int u = act ? csr_src[cbeg + lane] : 0;
        float p = act ? __expf(lrelu(als[u] + adv)) : 0.f;
        s_u[wslot][lane] = u;
        s_p[wslot][lane] = p;
        for (int i = 0; i < cnt; i += 12) {
            int e = i + g;
            int uu = s_u[wslot][e];
            float pp = s_p[wslot][e];
            uint4 w = {0u, 0u, 0u, 0u};
            if (gact) w = Ht4[(size_t)uu * 5 + li];
            if (gact) tsum += pp;
            fma8(a, w, pp);
        }
    }
    if (gact) {
#pragma unroll
        for (int j = 0; j < 8; ++j) s_red[wslot][g][li * 8 + j] = a[j];
        if (li == 0) s_red[wslot][g][40] = tsum;
    }
    bool fown = lane < DOUT;
    float accf = 0.f, T = 0.f;
#pragma unroll
    for (int g2 = 0; g2 < 12; ++g2) {
        if (fown) accf += s_red[wslot][g2][lane];
        T += s_red[wslot][g2][40];
    }
    float inv = 1.f / (T + 1e-16f);
    float z = fown ? (accf * inv + bias[lane]) : -1e30f;
    float zm = z;
#pragma unroll
    for (int off = 1; off < 64; off <<= 1) zm = fmaxf(zm, __shfl_xor(zm, off));
    float se = fown ? __expf(z - zm) : 0.f;
#pragma unroll
    for (int off = 1; off < 64; off <<= 1) se += __shfl_xor(se, off);
    float ls = zm + logf(se);
    if (fown) out[(size_t)v * DOUT + lane] = z - ls;
}

// ---------------- batch norm stats (float4-vectorized) ----------------
__global__ __launch_bounds__(256) void bn_stats_kernel(const float* __restrict__ X,
                                                       float* __restrict__ sums, float* __restrict__ sqs) {
    const int t = threadIdx.x;
    const int tid = blockIdx.x * 256 + t;
    const float4* X4 = (const float4*)X;
    float4 s = {0.f, 0.f, 0.f, 0.f}, q = {0.f, 0.f, 0.f, 0.f};
    for (int i = tid; i < N_NODES * 32; i += 500 * 256) {
        float4 vv = X4[i];
        s.x += vv.x; s.y += vv.y; s.z += vv.z; s.w += vv.w;
        q.x += vv.x * vv.x; q.y += vv.y * vv.y; q.z += vv.z * vv.z; q.w += vv.w * vv.w;
    }
    __shared__ float ls[1024], lq[1024];
    *(float4*)&ls[t * 4] = s;
    *(float4*)&lq[t * 4] = q;
    __syncthreads();
    if (t < 128) {
        int c4 = t >> 2, j = t & 3;
        float S = 0.f, Q = 0.f;
#pragma unroll
        for (int k = 0; k < 8; ++k) {
            S += ls[(c4 + 32 * k) * 4 + j];
            Q += lq[(c4 + 32 * k) * 4 + j];
        }
        atomicAdd(&sums[t], S);
        atomicAdd(&sqs[t], Q);
    }
}

// ---------------- launch ----------------
extern "C" void kernel_launch(void* const* d_in, const int* in_sizes, int n_in,
                              void* d_out, int out_size, void* d_ws, size_t ws_size,
                              hipStream_t stream) {
    (void)in_sizes; (void)n_in; (void)out_size; (void)ws_size;
    const float* x = (const float*)d_in[0];
    const int* ei = (const int*)d_in[1];
    const float* W0 = (const float*)d_in[2];
    const float* as0 = (const float*)d_in[3];
    const float* ad0 = (const float*)d_in[4];
    const float* b0 = (const float*)d_in[5];
    const float* W1 = (const float*)d_in[6];
    const float* as1 = (const float*)d_in[7];
    const float* ad1 = (const float*)d_in[8];
    const float* b1 = (const float*)d_in[9];
    const float* W2 = (const float*)d_in[10];
    const float* as2 = (const float*)d_in[11];
    const float* ad2 = (const float*)d_in[12];
    const float* b2 = (const float*)d_in[13];
    const float* g_bn0 = (const float*)d_in[14];
    const float* be_bn0 = (const float*)d_in[15];
    const float* g_bn1 = (const float*)d_in[16];
    const float* be_bn1 = (const float*)d_in[17];
    float* out = (float*)d_out;

    const int* srcv = ei;
    const int* dstv = ei + N_EDGES;

    char* p = (char*)d_ws;
    auto carve = [&](size_t bytes) {
        char* q = p;
        p += (bytes + 255) & ~(size_t)255;
        return q;
    };
    unsigned int* h_bf = (unsigned int*)carve((size_t)N_NODES * 64 * 4);  // f16 h (also as [N,40] rows)
    float* agg   = (float*)carve((size_t)N_NODES * DHID * 4);
    float* als   = (float*)carve((size_t)N_NODES * NH * 4);
    float* ald   = (float*)carve((size_t)N_NODES * NH * 4);
    int* row_ptr = (int*)carve((size_t)(N_NODES + 1) * 4);
    int* csr_src = (int*)carve((size_t)N_EDGES * 4);
    unsigned* part = (unsigned*)carve((size_t)N_EDGES * 4);
    int* bhist   = (int*)carve((PB + 512) * 4);
    float* sums0 = (float*)(bhist + PB);
    float* sqs0  = sums0 + 128;
    float* sums1 = sqs0 + 128;
    float* sqs1  = sums1 + 128;
    int* bucket_base = (int*)carve((PB + 1) * 4);
    int* cursor  = (int*)carve(PB * 4);

    const float bs0 = 1.0f + 1.0f / 25.001f;
    const float bs1 = 1.0f + 0.5f / 25.001f;

    const int RT64 = (N_NODES + 63) / 64;      // 782
    const int G128B = RT64 * 2;                // 1564
    const int G40B = RT64;                     // 782
    const int AB = (N_NODES * 64 + 255) / 256; // 12500
    const int PARTB = (N_EDGES + 4095) / 4096; // 196

    // ---- bucketed CSR build ----
    hipMemsetAsync(bhist, 0, (PB + 512) * 4, stream);
    bucket_hist_kernel<<<400, 256, 0, stream>>>(dstv, bhist);
    bucket_scan_kernel<<<1, PB, 0, stream>>>(bhist, bucket_base, cursor);
    partition_kernel<<<PARTB, 256, 0, stream>>>(srcv, dstv, cursor, part);
    bucket_csr_kernel<<<PB, 256, 0, stream>>>(part, bucket_base, row_ptr, csr_src);

    // ---- layer 0 ----
    gemm128_kernel<<<G128B, 256, 0, stream>>>(x, W0, as0, ad0, nullptr, nullptr, nullptr, nullptr, 1.f, 0, h_bf, als, ald);
    agg128_kernel<<<AB, 256, 0, stream>>>(row_ptr, csr_src, h_bf, als, ald, b0, agg);
    bn_stats_kernel<<<500, 256, 0, stream>>>(agg, sums0, sqs0);

    // ---- layer 1 (BN0 finalize+ELU fused into gemm) ----
    gemm128_kernel<<<G128B, 256, 0, stream>>>(agg, W1, as1, ad1, sums0, sqs0, g_bn0, be_bn0, bs0, 1, h_bf, als, ald);
    agg128_kernel<<<AB, 256, 0, stream>>>(row_ptr, csr_src, h_bf, als, ald, b1, agg);
    bn_stats_kernel<<<500, 256, 0, stream>>>(agg, sums1, sqs1);

    // ---- layer 2 (BN1 finalize+ELU fused) + log_softmax ----
    gemm40_kernel<<<G40B, 256, 0, stream>>>(agg, W2, as2, ad2, sums1, sqs1, g_bn1, be_bn1, bs1, (unsigned short*)h_bf, als, ald);
    agg40_kernel<<<AB, 256, 0, stream>>>(row_ptr, csr_src, (const uint4*)h_bf, als, ald, b2, out);
}

// Round 17
// 248.894 us; speedup vs baseline: 1.1259x; 1.0858x over previous
//
#include <hip/hip_runtime.h>
#include <math.h>

#define N_NODES 50000
#define N_EDGES 800000
#define DIN 128
#define DHID 128   /* H*HID */
#define NH 4
#define HID 32
#define DOUT 40

#define PB 128      /* dst buckets */
#define NPB 391     /* nodes per bucket: 391*128 = 50048 >= 50000 */

typedef __fp16 fp16x2 __attribute__((ext_vector_type(2)));
using s16x8 = __attribute__((ext_vector_type(8))) short;   // 8 bf16 (4 VGPRs) — guide-verified MFMA frag type
using f32x4v = __attribute__((ext_vector_type(4))) float;  // 4 f32 acc

static __device__ __forceinline__ float lrelu(float x) { return x > 0.f ? x : 0.2f * x; }

static __device__ __forceinline__ unsigned int pkh(float a, float b) {
    union { fp16x2 h2; unsigned int u; } cv;
    cv.h2 = __builtin_amdgcn_cvt_pkrtz(a, b);
    return cv.u;
}
static __device__ __forceinline__ unsigned short f2h(float a) {
    union { _Float16 h; unsigned short s; } cv;
    cv.h = (_Float16)a;
    return cv.s;
}
static __device__ __forceinline__ unsigned short f2bf(float f) {
    unsigned int u = __float_as_uint(f);
    u = (u + 0x7FFFu + ((u >> 16) & 1u)) >> 16;
    return (unsigned short)u;
}

// acc[0..7] += p * f16x8(w)  — unpack via f16->f32 (fuses to v_fma_mix)
static __device__ __forceinline__ void fma8(float* acc, uint4 w, float p) {
    union { unsigned int u; _Float16 h[2]; } c0, c1, c2, c3;
    c0.u = w.x; c1.u = w.y; c2.u = w.z; c3.u = w.w;
    acc[0] = fmaf((float)c0.h[0], p, acc[0]);
    acc[1] = fmaf((float)c0.h[1], p, acc[1]);
    acc[2] = fmaf((float)c1.h[0], p, acc[2]);
    acc[3] = fmaf((float)c1.h[1], p, acc[3]);
    acc[4] = fmaf((float)c2.h[0], p, acc[4]);
    acc[5] = fmaf((float)c2.h[1], p, acc[5]);
    acc[6] = fmaf((float)c3.h[0], p, acc[6]);
    acc[7] = fmaf((float)c3.h[1], p, acc[7]);
}

static __device__ __forceinline__ float4 bnelu4(float4 x, float4 sc, float4 sh, float bs) {
    float y0 = fmaf(x.x, sc.x, sh.x);
    float y1 = fmaf(x.y, sc.y, sh.y);
    float y2 = fmaf(x.z, sc.z, sh.z);
    float y3 = fmaf(x.w, sc.w, sh.w);
    y0 = (y0 > 0.f ? y0 : __expf(y0) - 1.f) * bs;
    y1 = (y1 > 0.f ? y1 : __expf(y1) - 1.f) * bs;
    y2 = (y2 > 0.f ? y2 : __expf(y2) - 1.f) * bs;
    y3 = (y3 > 0.f ? y3 : __expf(y3) - 1.f) * bs;
    return {y0, y1, y2, y3};
}

// ================= bucketed CSR build (XCD-local writes) =================
__global__ __launch_bounds__(256) void bucket_hist_kernel(const int* __restrict__ dstv, int* __restrict__ bhist) {
    __shared__ int h[PB];
    if (threadIdx.x < PB) h[threadIdx.x] = 0;
    __syncthreads();
    for (int i = blockIdx.x * blockDim.x + threadIdx.x; i < N_EDGES; i += gridDim.x * blockDim.x)
        atomicAdd(&h[(unsigned)dstv[i] / NPB], 1);
    __syncthreads();
    if (threadIdx.x < PB) atomicAdd(&bhist[threadIdx.x], h[threadIdx.x]);
}

__global__ __launch_bounds__(128) void bucket_scan_kernel(const int* __restrict__ bhist,
                                                          int* __restrict__ bucket_base, int* __restrict__ cursor) {
    __shared__ int sA[PB], sB[PB];
    int t = threadIdx.x;
    sA[t] = bhist[t];
    __syncthreads();
    int* s = sA; int* d2 = sB;
    for (int off = 1; off < PB; off <<= 1) {
        d2[t] = s[t] + (t >= off ? s[t - off] : 0);
        __syncthreads();
        int* tmp = s; s = d2; d2 = tmp;
    }
    int excl = s[t] - bhist[t];
    bucket_base[t] = excl;
    cursor[t] = excl;
    if (t == PB - 1) bucket_base[PB] = s[t];
}

// records packed as (src<<16)|dst — both < 65536
__global__ __launch_bounds__(256) void partition_kernel(const int* __restrict__ srcv, const int* __restrict__ dstv,
                                                        int* __restrict__ cursor, unsigned* __restrict__ part) {
    __shared__ unsigned rec[2048];
    __shared__ int cnt[PB], lofs[PB], gbase[PB];
    __shared__ int sA[PB], sB[PB];
    __shared__ int tot_s;
    const int t = threadIdx.x;
    const int base0 = blockIdx.x * 4096;
    for (int round = 0; round < 2; ++round) {
        int rbase = base0 + round * 2048;
        if (t < PB) cnt[t] = 0;
        __syncthreads();
        int myb[8]; int myr[8]; unsigned myrec[8];
#pragma unroll
        for (int i = 0; i < 8; ++i) {
            int e = rbase + i * 256 + t;
            bool valid = e < N_EDGES;
            int sv = valid ? srcv[e] : 0;
            int dv = valid ? dstv[e] : 0;
            myrec[i] = ((unsigned)sv << 16) | (unsigned)dv;
            int b = (unsigned)dv / NPB;
            myb[i] = valid ? b : -1;
            myr[i] = valid ? atomicAdd(&cnt[b], 1) : 0;
        }
        __syncthreads();
        if (t < PB) sA[t] = cnt[t];
        __syncthreads();
        int* s = sA; int* d2 = sB;
        for (int off = 1; off < PB; off <<= 1) {
            if (t < PB) d2[t] = s[t] + (t >= off ? s[t - off] : 0);
            __syncthreads();
            int* tmp = s; s = d2; d2 = tmp;
        }
        if (t < PB) {
            int c = cnt[t];
            lofs[t] = s[t] - c;
            gbase[t] = c > 0 ? atomicAdd(&cursor[t], c) : 0;
            if (t == PB - 1) tot_s = s[t];
        }
        __syncthreads();
#pragma unroll
        for (int i = 0; i < 8; ++i)
            if (myb[i] >= 0) rec[lofs[myb[i]] + myr[i]] = myrec[i];
        __syncthreads();
        int tot = tot_s;
#pragma unroll
        for (int i = 0; i < 8; ++i) {
            int lp = i * 256 + t;
            if (lp < tot) {
                unsigned r = rec[lp];
                int b = (r & 0xFFFFu) / NPB;
                part[gbase[b] + (lp - lofs[b])] = r;
            }
        }
        __syncthreads();
    }
}

__global__ __launch_bounds__(256) void bucket_csr_kernel(const unsigned* __restrict__ part, const int* __restrict__ bucket_base,
                                                         int* __restrict__ row_ptr, int* __restrict__ csr_src) {
    __shared__ int hist[512], sA[512], sB[512], cur[NPB];
    const int b = blockIdx.x, t = threadIdx.x;
    const int base = bucket_base[b];
    const int n = bucket_base[b + 1] - base;
    hist[t] = 0; hist[t + 256] = 0;
    __syncthreads();
    for (int i = t; i < n; i += 256)
        atomicAdd(&hist[(part[base + i] & 0xFFFFu) - b * NPB], 1);
    __syncthreads();
    sA[t] = hist[t]; sA[t + 256] = hist[t + 256];
    __syncthreads();
    int* s = sA; int* d2 = sB;
    for (int off = 1; off < 512; off <<= 1) {
        d2[t] = s[t] + (t >= off ? s[t - off] : 0);
        int u = t + 256;
        d2[u] = s[u] + (u >= off ? s[u - off] : 0);
        __syncthreads();
        int* tmp = s; s = d2; d2 = tmp;
    }
    for (int j = t; j < NPB; j += 256) {
        int node = b * NPB + j;
        int excl = s[j] - hist[j];
        if (node < N_NODES) row_ptr[node] = base + excl;
        cur[j] = excl;
    }
    if (b == PB - 1 && t == 0) row_ptr[N_NODES] = N_EDGES;
    __syncthreads();
    for (int i = t; i < n; i += 256) {
        unsigned r = part[base + i];
        int loc = (int)(r & 0xFFFFu) - b * NPB;
        int p = atomicAdd(&cur[loc], 1);
        csr_src[base + p] = (int)(r >> 16);
    }
}

// ---------------- gemm128: MFMA bf16, 64 rows x 128 cols per block ----------------
// 4 waves; wave w owns rows 16w..16w+15, all 8 col-tiles (16 cols each).
// A/B staged with consistent k-slot mapping: lane l -> k = ks*32 + (l>>4)*8 + j.
// C/D layout (HW-verified): col = lane&15, row = (lane>>4)*4 + reg.
__global__ __launch_bounds__(256) void gemm128_kernel(
    const float* __restrict__ X, const float* __restrict__ W,
    const float* __restrict__ a_src, const float* __restrict__ a_dst,
    const float* __restrict__ sums, const float* __restrict__ sqs,
    const float* __restrict__ gamma, const float* __restrict__ beta, float bscale, int apply_bn,
    unsigned short* __restrict__ Hout16, float* __restrict__ als, float* __restrict__ ald) {
    __shared__ unsigned int Xl[64][68];      // bf16 pairs; row = 136 bf16 (pad 8) -> 272 B stride
    __shared__ unsigned short Wf[16384];     // bf16 frags: [(ks*8+ct)*64 + slot]*8 + j
    __shared__ float scale_s[DHID], shift_s[DHID];
    const int t = threadIdx.x;
    const int w = t >> 6, l = t & 63;
    const int r0 = blockIdx.x * 64;

    if (apply_bn && t < DHID) {
        float mu = sums[t] * (1.f / N_NODES);
        float var = sqs[t] * (1.f / N_NODES) - mu * mu;
        float sc = gamma[t] * rsqrtf(var + 1e-5f);
        scale_s[t] = sc;
        shift_s[t] = beta[t] - mu * sc;
    }
    __syncthreads();

    // ---- stage X: 64 rows x 128 k (f32 -> bf16, optional BN/ELU) ----
    {
        int sr = t >> 2, sa = t & 3;
        int gr = r0 + sr; gr = gr < N_NODES ? gr : N_NODES - 1;
        const float* Xrow = X + (size_t)gr * 128;
#pragma unroll
        for (int q = 0; q < 4; ++q) {
            int k0 = q * 32 + sa * 8;
            float4 xa = *(const float4*)(Xrow + k0);
            float4 xb = *(const float4*)(Xrow + k0 + 4);
            if (apply_bn) {
                xa = bnelu4(xa, *(const float4*)(scale_s + k0), *(const float4*)(shift_s + k0), bscale);
                xb = bnelu4(xb, *(const float4*)(scale_s + k0 + 4), *(const float4*)(shift_s + k0 + 4), bscale);
            }
            unsigned int* dst = &Xl[sr][k0 >> 1];
            dst[0] = (unsigned)f2bf(xa.x) | ((unsigned)f2bf(xa.y) << 16);
            dst[1] = (unsigned)f2bf(xa.z) | ((unsigned)f2bf(xa.w) << 16);
            dst[2] = (unsigned)f2bf(xb.x) | ((unsigned)f2bf(xb.y) << 16);
            dst[3] = (unsigned)f2bf(xb.z) | ((unsigned)f2bf(xb.w) << 16);
        }
    }
    // ---- stage W: 128x128 f32 -> bf16 fragment order ----
#pragma unroll 4
    for (int i = 0; i < 64; ++i) {
        int idx = i * 256 + t;
        int k = idx >> 7, c = idx & 127;
        float wv = W[idx];
        int ks = k >> 5, kr = k & 31;
        int lfrag = ((kr >> 3) << 4) | (c & 15);
        int slot = lfrag ^ ((lfrag >> 3) & 3);
        Wf[(((ks << 3) + (c >> 4)) * 64 + slot) * 8 + (kr & 7)] = f2bf(wv);
    }
    __syncthreads();

    // ---- MFMA ----
    f32x4v acc[8];
#pragma unroll
    for (int ct = 0; ct < 8; ++ct) acc[ct] = {0.f, 0.f, 0.f, 0.f};
    const int cl = l & 15, g = l >> 4;
    const int slotR = l ^ ((l >> 3) & 3);
    const unsigned short* XrowL = (const unsigned short*)&Xl[16 * w + cl][0];
#pragma unroll
    for (int ks = 0; ks < 4; ++ks) {
        s16x8 afrag = *(const s16x8*)(XrowL + ks * 32 + g * 8);
#pragma unroll
        for (int ct = 0; ct < 8; ++ct) {
            s16x8 bfrag = *(const s16x8*)&Wf[(((ks << 3) + ct) * 64 + slotR) * 8];
            acc[ct] = __builtin_amdgcn_mfma_f32_16x16x32_bf16(afrag, bfrag, acc[ct], 0, 0, 0);
        }
    }

    // ---- epilogue: h store + per-head als/ald ----
    float asv[8], adv[8];
#pragma unroll
    for (int ct = 0; ct < 8; ++ct) {
        asv[ct] = a_src[ct * 16 + cl];
        adv[ct] = a_dst[ct * 16 + cl];
    }
#pragma unroll
    for (int r = 0; r < 4; ++r) {
        int node = r0 + 16 * w + 4 * g + r;
        bool valid = node < N_NODES;
        if (valid) {
#pragma unroll
            for (int ct = 0; ct < 8; ++ct)
                Hout16[(size_t)node * 128 + ct * 16 + cl] = f2h(acc[ct][r]);
        }
        float ps[4], pd[4];
#pragma unroll
        for (int h = 0; h < 4; ++h) {
            ps[h] = acc[2 * h][r] * asv[2 * h] + acc[2 * h + 1][r] * asv[2 * h + 1];
            pd[h] = acc[2 * h][r] * adv[2 * h] + acc[2 * h + 1][r] * adv[2 * h + 1];
#pragma unroll
            for (int off = 1; off < 16; off <<= 1) {
                ps[h] += __shfl_xor(ps[h], off);
                pd[h] += __shfl_xor(pd[h], off);
            }
        }
        if (valid && cl == 0) {
#pragma unroll
            for (int h = 0; h < 4; ++h) {
                als[node * 4 + h] = ps[h];
                ald[node * 4 + h] = pd[h];
            }
        }
    }
}

// ---------------- gemm40: [N,128]@[128,40] (+ fused BN-finalize/ELU) + als/ald, f16 h out ----------------
__global__ __launch_bounds__(256) void gemm40_kernel(
    const float* __restrict__ X, const float* __restrict__ W,
    const float* __restrict__ a_src, const float* __restrict__ a_dst,
    const float* __restrict__ sums, const float* __restrict__ sqs,
    const float* __restrict__ gamma, const float* __restrict__ beta, float bscale,
    unsigned short* __restrict__ Hout, float* __restrict__ als, float* __restrict__ ald) {
    __shared__ float Xs[64][36];
    __shared__ float Ws[40][36];
    __shared__ float scale_s[DHID], shift_s[DHID];
    const int t = threadIdx.x;
    const int tx = t & 7, ty = t >> 3;
    const int r0 = blockIdx.x * 64;
    const int sr = t >> 2, sa = t & 3;

    if (t < DHID) {
        float mu = sums[t] * (1.f / N_NODES);
        float var = sqs[t] * (1.f / N_NODES) - mu * mu;
        float sc = gamma[t] * rsqrtf(var + 1e-5f);
        scale_s[t] = sc;
        shift_s[t] = beta[t] - mu * sc;
    }
    __syncthreads();

    int gr = r0 + sr; gr = gr < N_NODES ? gr : N_NODES - 1;
    const float* Xrow = X + (size_t)gr * 128;
    float4 xpreA = bnelu4(*(const float4*)(Xrow + 8 * sa),
                          *(const float4*)(scale_s + 8 * sa), *(const float4*)(shift_s + 8 * sa), bscale);
    float4 xpreB = bnelu4(*(const float4*)(Xrow + 8 * sa + 4),
                          *(const float4*)(scale_s + 8 * sa + 4), *(const float4*)(shift_s + 8 * sa + 4), bscale);
    float wpre[5];
#pragma unroll
    for (int i = 0; i < 5; ++i) wpre[i] = W[t + 256 * i];

    float acc[2][5];
#pragma unroll
    for (int i = 0; i < 2; ++i)
#pragma unroll
        for (int j = 0; j < 5; ++j) acc[i][j] = 0.f;

    for (int step = 0; step < 4; ++step) {
        __syncthreads();
        *(float4*)&Xs[sr][8 * sa] = xpreA;
        *(float4*)&Xs[sr][8 * sa + 4] = xpreB;
#pragma unroll
        for (int i = 0; i < 5; ++i) {
            int idx = t + 256 * i;
            Ws[idx % 40][idx / 40] = wpre[i];
        }
        if (step < 3) {
            int k0 = (step + 1) * 32;
            xpreA = bnelu4(*(const float4*)(Xrow + k0 + 8 * sa),
                           *(const float4*)(scale_s + k0 + 8 * sa), *(const float4*)(shift_s + k0 + 8 * sa), bscale);
            xpreB = bnelu4(*(const float4*)(Xrow + k0 + 8 * sa + 4),
                           *(const float4*)(scale_s + k0 + 8 * sa + 4), *(const float4*)(shift_s + k0 + 8 * sa + 4), bscale);
#pragma unroll
            for (int i = 0; i < 5; ++i) wpre[i] = W[k0 * 40 + t + 256 * i];
        }
        __syncthreads();
#pragma unroll
        for (int kk4 = 0; kk4 < 8; ++kk4) {
            float4 xa = *(const float4*)&Xs[2 * ty][4 * kk4];
            float4 xb = *(const float4*)&Xs[2 * ty + 1][4 * kk4];
#pragma unroll
            for (int j = 0; j < 5; ++j) {
                float4 wv = *(const float4*)&Ws[tx + 8 * j][4 * kk4];
                acc[0][j] = fmaf(xa.x, wv.x, acc[0][j]);
                acc[0][j] = fmaf(xa.y, wv.y, acc[0][j]);
                acc[0][j] = fmaf(xa.z, wv.z, acc[0][j]);
                acc[0][j] = fmaf(xa.w, wv.w, acc[0][j]);
                acc[1][j] = fmaf(xb.x, wv.x, acc[1][j]);
                acc[1][j] = fmaf(xb.y, wv.y, acc[1][j]);
                acc[1][j] = fmaf(xb.z, wv.z, acc[1][j]);
                acc[1][j] = fmaf(xb.w, wv.w, acc[1][j]);
            }
        }
    }
    float asv[5], adv[5];
#pragma unroll
    for (int j = 0; j < 5; ++j) {
        asv[j] = a_src[tx + 8 * j];
        adv[j] = a_dst[tx + 8 * j];
    }
#pragma unroll
    for (int i = 0; i < 2; ++i) {
        int r = r0 + 2 * ty + i;
        bool valid = r < N_NODES;
        if (valid) {
#pragma unroll
            for (int j = 0; j < 5; ++j)
                Hout[(size_t)r * 40 + tx + 8 * j] = f2h(acc[i][j]);
        }
        float ps = 0.f, pd = 0.f;
#pragma unroll
        for (int j = 0; j < 5; ++j) {
            ps = fmaf(acc[i][j], asv[j], ps);
            pd = fmaf(acc[i][j], adv[j], pd);
        }
#pragma unroll
        for (int off = 1; off < 8; off <<= 1) {
            ps += __shfl_xor(ps, off);
            pd += __shfl_xor(pd, off);
        }
        if (valid && tx == 0) {
            als[r] = ps;
            ald[r] = pd;
        }
    }
}

// ---------------- agg128: one wave per node; 2-deep unrolled 8-edge gather ----------------
__global__ __launch_bounds__(256) void agg128_kernel(
    const int* __restrict__ row_ptr, const int* __restrict__ csr_src,
    const unsigned int* __restrict__ Ht, const float* __restrict__ als, const float* __restrict__ ald,
    const float* __restrict__ bias, float* __restrict__ out) {
    __shared__ float s_p[4][256];
    __shared__ int s_u[4][64];
    int v = (blockIdx.x * blockDim.x + threadIdx.x) >> 6;
    v = __builtin_amdgcn_readfirstlane(v);
    int lane = threadIdx.x & 63;
    int wslot = threadIdx.x >> 6;
    if (v >= N_NODES) return;
    int beg = row_ptr[v], end = row_ptr[v + 1];
    float4 ad4 = *(const float4*)(ald + (size_t)v * 4);
    const int g = lane >> 4;
    const int li = lane & 15;
    const int hh = li >> 2;
    float tsum = 0.f;
    float acc[8];
#pragma unroll
    for (int j = 0; j < 8; ++j) acc[j] = 0.f;

    for (int cbeg = beg; cbeg < end; cbeg += 64) {
        int cnt = min(64, end - cbeg);
        bool act = lane < cnt;
        int u = act ? csr_src[cbeg + lane] : 0;
        float p0, p1, p2, p3;
        if (act) {
            float4 s4 = *(const float4*)(als + (size_t)u * 4);
            p0 = __expf(lrelu(s4.x + ad4.x));
            p1 = __expf(lrelu(s4.y + ad4.y));
            p2 = __expf(lrelu(s4.z + ad4.z));
            p3 = __expf(lrelu(s4.w + ad4.w));
        } else {
            p0 = p1 = p2 = p3 = 0.f;
        }
        s_u[wslot][lane] = u;
        float4 pv = {p0, p1, p2, p3};
        *(float4*)&s_p[wslot][lane * 4] = pv;
        for (int i = 0; i < cnt; i += 8) {
            int ea = i + g;
            int eb = i + 4 + g;
            int ua = s_u[wslot][ea];
            int ub = s_u[wslot][eb];
            float pa = s_p[wslot][ea * 4 + hh];
            float pb = s_p[wslot][eb * 4 + hh];
            uint4 wa = *(const uint4*)(Ht + (size_t)ua * 64 + li * 4);
            uint4 wb = *(const uint4*)(Ht + (size_t)ub * 64 + li * 4);
            tsum += pa + pb;
            fma8(acc, wa, pa);
            fma8(acc, wb, pb);
        }
    }
#pragma unroll
    for (int j = 0; j < 8; ++j) {
        acc[j] += __shfl_xor(acc[j], 16);
        acc[j] += __shfl_xor(acc[j], 32);
    }
    tsum += __shfl_xor(tsum, 16);
    tsum += __shfl_xor(tsum, 32);
    float inv = 1.f / (tsum + 1e-16f);
    if (g == 0) {
        float4 b0 = *(const float4*)(bias + 8 * li);
        float4 b1 = *(const float4*)(bias + 8 * li + 4);
        float4 o0 = {acc[0] * inv + b0.x, acc[1] * inv + b0.y, acc[2] * inv + b0.z, acc[3] * inv + b0.w};
        float4 o1 = {acc[4] * inv + b1.x, acc[5] * inv + b1.y, acc[6] * inv + b1.z, acc[7] * inv + b1.w};
        *(float4*)(out + (size_t)v * DHID + 8 * li) = o0;
        *(float4*)(out + (size_t)v * DHID + 8 * li + 4) = o1;
    }
}

// ---------------- agg40: one wave per node; 12-edge-parallel uint4 gather + log_softmax ----------------
__global__ __launch_bounds__(256) void agg40_kernel(
    const int* __restrict__ row_ptr, const int* __restrict__ csr_src,
    const uint4* __restrict__ Ht4, const float* __restrict__ als, const float* __restrict__ ald,
    const float* __restrict__ bias, float* __restrict__ out) {
    __shared__ float s_p[4][76];
    __shared__ int s_u[4][76];
    __shared__ float s_red[4][12][41];
    int v = (blockIdx.x * blockDim.x + threadIdx.x) >> 6;
    v = __builtin_amdgcn_readfirstlane(v);
    int lane = threadIdx.x & 63;
    int wslot = threadIdx.x >> 6;
    if (v >= N_NODES) return;
    int beg = row_ptr[v], end = row_ptr[v + 1];
    float adv = ald[v];
    const int g = lane / 5;
    const int li = lane - g * 5;
    const bool gact = lane < 60;
    if (lane < 12) { s_u[wslot][64 + lane] = 0; s_p[wslot][64 + lane] = 0.f; }
    float tsum = 0.f;
    float a[8];
#pragma unroll
    for (int j = 0; j < 8; ++j) a[j] = 0.f;

    for (int cbeg = beg; cbeg < end; cbeg += 64) {
        int cnt = min(64, end - cbeg);
        bool act = lane < cnt;
        int u = act ? csr_src[cbeg + lane] : 0;
        float p = act ? __expf(lrelu(als[u] + adv)) : 0.f;
        s_u[wslot][lane] = u;
        s_p[wslot][lane] = p;
        for (int i = 0; i < cnt; i += 12) {
            int e = i + g;
            int uu = s_u[wslot][e];
            float pp = s_p[wslot][e];
            uint4 w = {0u, 0u, 0u, 0u};
            if (gact) w = Ht4[(size_t)uu * 5 + li];
            if (gact) tsum += pp;
            fma8(a, w, pp);
        }
    }
    if (gact) {
#pragma unroll
        for (int j = 0; j < 8; ++j) s_red[wslot][g][li * 8 + j] = a[j];
        if (li == 0) s_red[wslot][g][40] = tsum;
    }
    bool fown = lane < DOUT;
    float accf = 0.f, T = 0.f;
#pragma unroll
    for (int g2 = 0; g2 < 12; ++g2) {
        if (fown) accf += s_red[wslot][g2][lane];
        T += s_red[wslot][g2][40];
    }
    float inv = 1.f / (T + 1e-16f);
    float z = fown ? (accf * inv + bias[lane]) : -1e30f;
    float zm = z;
#pragma unroll
    for (int off = 1; off < 64; off <<= 1) zm = fmaxf(zm, __shfl_xor(zm, off));
    float se = fown ? __expf(z - zm) : 0.f;
#pragma unroll
    for (int off = 1; off < 64; off <<= 1) se += __shfl_xor(se, off);
    float ls = zm + logf(se);
    if (fown) out[(size_t)v * DOUT + lane] = z - ls;
}

// ---------------- batch norm stats (float4-vectorized) ----------------
__global__ __launch_bounds__(256) void bn_stats_kernel(const float* __restrict__ X,
                                                       float* __restrict__ sums, float* __restrict__ sqs) {
    const int t = threadIdx.x;
    const int tid = blockIdx.x * 256 + t;
    const float4* X4 = (const float4*)X;
    float4 s = {0.f, 0.f, 0.f, 0.f}, q = {0.f, 0.f, 0.f, 0.f};
    for (int i = tid; i < N_NODES * 32; i += 500 * 256) {
        float4 vv = X4[i];
        s.x += vv.x; s.y += vv.y; s.z += vv.z; s.w += vv.w;
        q.x += vv.x * vv.x; q.y += vv.y * vv.y; q.z += vv.z * vv.z; q.w += vv.w * vv.w;
    }
    __shared__ float ls[1024], lq[1024];
    *(float4*)&ls[t * 4] = s;
    *(float4*)&lq[t * 4] = q;
    __syncthreads();
    if (t < 128) {
        int c4 = t >> 2, j = t & 3;
        float S = 0.f, Q = 0.f;
#pragma unroll
        for (int k = 0; k < 8; ++k) {
            S += ls[(c4 + 32 * k) * 4 + j];
            Q += lq[(c4 + 32 * k) * 4 + j];
        }
        atomicAdd(&sums[t], S);
        atomicAdd(&sqs[t], Q);
    }
}

// ---------------- launch ----------------
extern "C" void kernel_launch(void* const* d_in, const int* in_sizes, int n_in,
                              void* d_out, int out_size, void* d_ws, size_t ws_size,
                              hipStream_t stream) {
    (void)in_sizes; (void)n_in; (void)out_size; (void)ws_size;
    const float* x = (const float*)d_in[0];
    const int* ei = (const int*)d_in[1];
    const float* W0 = (const float*)d_in[2];
    const float* as0 = (const float*)d_in[3];
    const float* ad0 = (const float*)d_in[4];
    const float* b0 = (const float*)d_in[5];
    const float* W1 = (const float*)d_in[6];
    const float* as1 = (const float*)d_in[7];
    const float* ad1 = (const float*)d_in[8];
    const float* b1 = (const float*)d_in[9];
    const float* W2 = (const float*)d_in[10];
    const float* as2 = (const float*)d_in[11];
    const float* ad2 = (const float*)d_in[12];
    const float* b2 = (const float*)d_in[13];
    const float* g_bn0 = (const float*)d_in[14];
    const float* be_bn0 = (const float*)d_in[15];
    const float* g_bn1 = (const float*)d_in[16];
    const float* be_bn1 = (const float*)d_in[17];
    float* out = (float*)d_out;

    const int* srcv = ei;
    const int* dstv = ei + N_EDGES;

    char* p = (char*)d_ws;
    auto carve = [&](size_t bytes) {
        char* q = p;
        p += (bytes + 255) & ~(size_t)255;
        return q;
    };
    unsigned int* h_bf = (unsigned int*)carve((size_t)N_NODES * 64 * 4);  // f16 h (also as [N,40] rows)
    float* agg   = (float*)carve((size_t)N_NODES * DHID * 4);
    float* als   = (float*)carve((size_t)N_NODES * NH * 4);
    float* ald   = (float*)carve((size_t)N_NODES * NH * 4);
    int* row_ptr = (int*)carve((size_t)(N_NODES + 1) * 4);
    int* csr_src = (int*)carve((size_t)N_EDGES * 4);
    unsigned* part = (unsigned*)carve((size_t)N_EDGES * 4);
    int* bhist   = (int*)carve((PB + 512) * 4);
    float* sums0 = (float*)(bhist + PB);
    float* sqs0  = sums0 + 128;
    float* sums1 = sqs0 + 128;
    float* sqs1  = sums1 + 128;
    int* bucket_base = (int*)carve((PB + 1) * 4);
    int* cursor  = (int*)carve(PB * 4);

    const float bs0 = 1.0f + 1.0f / 25.001f;
    const float bs1 = 1.0f + 0.5f / 25.001f;

    const int RT64 = (N_NODES + 63) / 64;      // 782
    const int G128B = RT64;                    // 782 (MFMA: 64 rows x 128 cols per block)
    const int G40B = RT64;                     // 782
    const int AB = (N_NODES * 64 + 255) / 256; // 12500
    const int PARTB = (N_EDGES + 4095) / 4096; // 196

    // ---- bucketed CSR build ----
    hipMemsetAsync(bhist, 0, (PB + 512) * 4, stream);
    bucket_hist_kernel<<<400, 256, 0, stream>>>(dstv, bhist);
    bucket_scan_kernel<<<1, PB, 0, stream>>>(bhist, bucket_base, cursor);
    partition_kernel<<<PARTB, 256, 0, stream>>>(srcv, dstv, cursor, part);
    bucket_csr_kernel<<<PB, 256, 0, stream>>>(part, bucket_base, row_ptr, csr_src);

    // ---- layer 0 ----
    gemm128_kernel<<<G128B, 256, 0, stream>>>(x, W0, as0, ad0, nullptr, nullptr, nullptr, nullptr, 1.f, 0,
                                              (unsigned short*)h_bf, als, ald);
    agg128_kernel<<<AB, 256, 0, stream>>>(row_ptr, csr_src, h_bf, als, ald, b0, agg);
    bn_stats_kernel<<<500, 256, 0, stream>>>(agg, sums0, sqs0);

    // ---- layer 1 (BN0 finalize+ELU fused into gemm) ----
    gemm128_kernel<<<G128B, 256, 0, stream>>>(agg, W1, as1, ad1, sums0, sqs0, g_bn0, be_bn0, bs0, 1,
                                              (unsigned short*)h_bf, als, ald);
    agg128_kernel<<<AB, 256, 0, stream>>>(row_ptr, csr_src, h_bf, als, ald, b1, agg);
    bn_stats_kernel<<<500, 256, 0, stream>>>(agg, sums1, sqs1);

    // ---- layer 2 (BN1 finalize+ELU fused) + log_softmax ----
    gemm40_kernel<<<G40B, 256, 0, stream>>>(agg, W2, as2, ad2, sums1, sqs1, g_bn1, be_bn1, bs1, (unsigned short*)h_bf, als, ald);
    agg40_kernel<<<AB, 256, 0, stream>>>(row_ptr, csr_src, (const uint4*)h_bf, als, ald, b2, out);
}